// Round 3
// baseline (839.779 us; speedup 1.0000x reference)
//
#include <hip/hip_runtime.h>

#define FEAT 41024
#define HID  256
#define BATCH 2048
#define MTOT 4096
#define MT 64
#define BK 64
#define NBK (FEAT / BK)                    /* 641 */
#define ACCN ((size_t)MTOT * HID)          /* 1,048,576 floats = 4 MB */
#define WH_BYTES ((size_t)HID * FEAT * 2)  /* 21,004,288 bytes, packed f16 W_in */
#define SLAB_ELTS 16384                    /* HID*BK f16 per k-slab in pack */

typedef float    f32x4  __attribute__((ext_vector_type(4)));
typedef float    f32x16 __attribute__((ext_vector_type(16)));
typedef _Float16 f16x4  __attribute__((ext_vector_type(4)));
typedef _Float16 f16x8  __attribute__((ext_vector_type(8)));

// ---------------- zero kernel (atomic-fallback path only) ----------------
__global__ __launch_bounds__(512) void zero_ws_k(float* __restrict__ p) {
    int i = blockIdx.x * 512 + threadIdx.x;
    ((f32x4*)p)[i] = (f32x4)(0.0f);
}

// ---------------- W_in fp32 -> f16 fragment-linear pack (one-shot) ----------------
// One block per k-slab t. Output layout: frag = wn*8 + ks*2 + nf (0..31), lane l, elem e:
//   P[t*16384 + frag*512 + l*8 + e] = (f16) W[wn*64 + nf*32 + (l&31)][t*64 + (ks*2+(l>>5))*8 + e]
// This is byte-identical to what R2's verified LDS staging+swizzle delivered to the
// MFMA B-operand, so gemm numerics are unchanged.
__global__ __launch_bounds__(256) void pack_w_k(
    const float* __restrict__ W, _Float16* __restrict__ P)
{
    __shared__ _Float16 Ls[256 * 64];  // 32 KB: W[0:256][t*64 : t*64+64] in f16
    const int t = blockIdx.x, tid = threadIdx.x;
    const int rr = tid >> 3, cc = tid & 7;
    #pragma unroll
    for (int u = 0; u < 8; ++u) {
        const int row = u * 32 + rr;
        const float* src = W + (size_t)row * FEAT + t * 64 + cc * 8;
        f32x4 v0 = *(const f32x4*)src;
        f32x4 v1 = *(const f32x4*)(src + 4);
        f16x8 h;
        #pragma unroll
        for (int e = 0; e < 4; ++e) { h[e] = (_Float16)v0[e]; h[e + 4] = (_Float16)v1[e]; }
        *(f16x8*)&Ls[row * 64 + cc * 8] = h;
    }
    __syncthreads();
    #pragma unroll
    for (int u = 0; u < 8; ++u) {
        const int flat = u * 256 + tid;          // 0..2047: one 16B output chunk
        const int frag = flat >> 6, l = flat & 63;
        const int wn = frag >> 3, ks = (frag >> 1) & 3, nf = frag & 1;
        const int row = wn * 64 + nf * 32 + (l & 31);
        const int kc  = ks * 2 + (l >> 5);
        *(f16x8*)&P[(size_t)t * SLAB_ELTS + (size_t)flat * 8] =
            *(const f16x8*)&Ls[row * 64 + kc * 8];
    }
}

// ---------------- input-layer GEMM: [4096,41024] x [41024,256]^T ----------------
// 512 threads = 8 waves (2m x 4n), block tile 64(M) x 256(N), wave tile 32x64.
// R2 post-mortem: the kernel was LDS-port-bound (~136 KB LDS traffic per block-iter
// ~= the whole 3540-cyc iteration). Fix: B never touches LDS -- fragment-packed W is
// loaded straight into registers (8 coalesced 1KB dwordx4 per wave per slab, from
// L2/LLC), double-buffered, compiler-managed vmcnt. A keeps reg-stage -> XOR-swizzled
// LDS (16 KB dbuf), the only LDS user (40 KB/block-iter). One raw s_barrier per iter.
__global__ __launch_bounds__(512, 4) void gemm_in_k(
    const float* __restrict__ wfeat, const float* __restrict__ bfeat,
    const _Float16* __restrict__ packW, float* __restrict__ part,
    int ksplit, int use_atomic)
{
    __shared__ __align__(16) _Float16 As[2][MT * BK];    // 2 x 8 KB

    const int tid   = threadIdx.x;
    const int mtile = blockIdx.x;
    const int split = blockIdx.y;
    const int it_beg = (split * NBK) / ksplit;
    const int it_end = ((split + 1) * NBK) / ksplit;
    const int L = it_end - it_beg;

    const int m0 = mtile * MT;  // block entirely white or entirely black rows
    const float* Aptr = (m0 < BATCH) ? (wfeat + (size_t)m0 * FEAT)
                                     : (bfeat + (size_t)(m0 - BATCH) * FEAT);

    // A staging: thread -> (row 0..63, 16B chunk 0..7); one f16x8 chunk per thread
    const int arow = tid >> 3;
    const int aqk  = tid & 7;
    const float* Asrc = Aptr + (size_t)arow * FEAT + aqk * 8;
    const int ac = aqk ^ (arow & 7);                     // XOR-swizzled chunk slot

    const int wid = tid >> 6, lane = tid & 63;
    const int l31 = lane & 31, lh = lane >> 5;
    const int wm  = wid >> 2;                            // 0..1
    const int wn  = wid & 3;                             // 0..3

    // B fragments: wave-contiguous 8 KB strip per slab, 8 x 1KB coalesced loads
    const _Float16* Bb = packW + (size_t)it_beg * SLAB_ELTS + wn * 4096 + lane * 8;

    f32x16 acc[2];
    acc[0] = (f32x16)(0.0f);
    acc[1] = (f32x16)(0.0f);

    f16x8 bcur[8], bnxt[8];
    f32x4 pa0[2], pa1[2];

    // ---- prologue: A(0)+B(0) now; A(1)+B(1) in flight; cvt A(0) -> As[0] ----
    {
        const int k0 = it_beg * BK;
        f32x4 a0 = *(const f32x4*)(Asrc + k0);
        f32x4 a1 = *(const f32x4*)(Asrc + k0 + 4);
        #pragma unroll
        for (int f = 0; f < 8; ++f) bcur[f] = *(const f16x8*)(Bb + f * 512);
        if (L > 1) {
            const float* s = Asrc + k0 + BK;
            pa0[0] = *(const f32x4*)s;
            pa0[1] = *(const f32x4*)(s + 4);
            #pragma unroll
            for (int f = 0; f < 8; ++f)
                bnxt[f] = *(const f16x8*)(Bb + SLAB_ELTS + f * 512);
        }
        f16x8 h;
        #pragma unroll
        for (int e = 0; e < 4; ++e) { h[e] = (_Float16)a0[e]; h[e + 4] = (_Float16)a1[e]; }
        *(f16x8*)&As[0][arow * BK + ac * 8] = h;
        asm volatile("s_waitcnt lgkmcnt(0)" ::: "memory");
        __builtin_amdgcn_sched_barrier(0);
        __builtin_amdgcn_s_barrier();
    }

    // entry invariants: As[bufc]=A(i); bC=B(i); other b-set=B(i+1) in flight;
    // paC=A(i+1) raw in flight; paN free.
    auto iter_body = [&](int i, int bufc, f16x8 (&bC)[8],
                         f32x4 (&paC)[2], f32x4 (&paN)[2]) {
        const bool hasW = (i + 1 < L);
        const bool has2 = (i + 2 < L);

        if (has2) {  // issue A(i+2) raw loads (HBM; waited next iteration)
            const float* s = Asrc + (size_t)(it_beg + i + 2) * BK;
            paN[0] = *(const f32x4*)s;
            paN[1] = *(const f32x4*)(s + 4);
        }
        if (hasW) {  // cvt A(i+1) -> other LDS buffer (safe: A(i-1) readers done)
            f16x8 h;
            #pragma unroll
            for (int e = 0; e < 4; ++e) {
                h[e]     = (_Float16)paC[0][e];
                h[e + 4] = (_Float16)paC[1][e];
            }
            *(f16x8*)&As[bufc ^ 1][arow * BK + ac * 8] = h;
        }

        // MFMA over slab i: A frags from LDS, B frags from registers
        #pragma unroll
        for (int ks = 0; ks < 4; ++ks) {
            const int r = wm * 32 + l31;
            const int c = (ks * 2 + lh) ^ (r & 7);
            const f16x8 afr = *(const f16x8*)&As[bufc][r * BK + c * 8];
            acc[0] = __builtin_amdgcn_mfma_f32_32x32x16_f16(afr, bC[ks * 2 + 0], acc[0], 0, 0, 0);
            acc[1] = __builtin_amdgcn_mfma_f32_32x32x16_f16(afr, bC[ks * 2 + 1], acc[1], 0, 0, 0);
        }

        if (has2) {  // refill just-consumed b-set with B(i+2) (waited in iter i+2)
            #pragma unroll
            for (int f = 0; f < 8; ++f)
                bC[f] = *(const f16x8*)(Bb + (size_t)(i + 2) * SLAB_ELTS + f * 512);
        }

        if (hasW) {
            asm volatile("s_waitcnt lgkmcnt(0)" ::: "memory");  // A ds_write visible
            __builtin_amdgcn_sched_barrier(0);
            __builtin_amdgcn_s_barrier();                       // A(i+1) buffer ready
        }
    };

    int i = 0;
    while (true) {
        iter_body(i, 0, bcur, pa0, pa1);
        if (++i == L) break;
        iter_body(i, 1, bnxt, pa1, pa0);
        if (++i == L) break;
    }

    // epilogue: C/D layout col=lane&31, row=(reg&3)+8*(reg>>2)+4*(lane>>5)
    float* dst = part + (use_atomic ? (size_t)0 : (size_t)split * ACCN);
    #pragma unroll
    for (int nf = 0; nf < 2; ++nf) {
        const int gcol = wn * 64 + nf * 32 + l31;
        #pragma unroll
        for (int r = 0; r < 16; ++r) {
            const int rrow = (r & 3) + 8 * (r >> 2) + 4 * lh;
            const int grow = m0 + wm * 32 + rrow;
            const size_t idx = (size_t)grow * HID + gcol;
            if (use_atomic) atomicAdd(&dst[idx], acc[nf][r]);
            else            dst[idx] = acc[nf][r];
        }
    }
}

// ---------------- split-K reduce + bias/relu + tiny MLP ----------------
// 256 blocks x 256 threads; wave handles 2 batch rows. Lane owns MLP output i=lane&31;
// half-waves split the 512-wide concat dimension.
__global__ __launch_bounds__(256) void mlp_k(
    const float* __restrict__ part, int nparts,
    const float* __restrict__ b_in,
    const float* __restrict__ W_h1, const float* __restrict__ b_h1,
    const float* __restrict__ W_h2, const float* __restrict__ b_h2,
    const float* __restrict__ W_out, const float* __restrict__ b_out,
    float* __restrict__ out)
{
    __shared__ _Float16 W1h[512 * 32];  // transposed [j][i], XOR-swizzled, 32 KB
    __shared__ float    W2T[32 * 33];   // transposed [ii][i'], padded
    __shared__ float    Wo[32];
    __shared__ float    cbuf[4 * 512];  // per-wave combined vector

    const int tid = threadIdx.x;
    #pragma unroll
    for (int u = 0; u < 64; ++u) {
        const int f = tid + 256 * u;
        const int i = f >> 9, j = f & 511;
        W1h[j * 32 + (i ^ (j & 31))] = (_Float16)W_h1[i * 512 + j];
    }
    #pragma unroll
    for (int u = 0; u < 4; ++u) {
        const int f = tid + 256 * u;
        const int a = f >> 5, b = f & 31;
        W2T[b * 33 + a] = W_h2[a * 32 + b];
    }
    if (tid < 32) Wo[tid] = W_out[tid];
    __syncthreads();

    const int wid = tid >> 6, lane = tid & 63, l31 = lane & 31, lh = lane >> 5;
    const float bh1 = b_h1[l31], bh2 = b_h2[l31], bo = b_out[0];
    float* cw = &cbuf[wid * 512];

    for (int r = 0; r < 2; ++r) {
        const int row = blockIdx.x * 8 + wid * 2 + r;
        const int jb  = lane * 8;  // 0..504; lanes 0-31 white half, 32-63 black half
        const size_t srow = (size_t)(lh ? (row + BATCH) : row) * HID + (jb & 255);
        f32x4 v0 = (f32x4)(0.0f), v1 = (f32x4)(0.0f);
        for (int s = 0; s < nparts; ++s) {
            const float* p = part + (size_t)s * ACCN + srow;
            v0 += *(const f32x4*)p;
            v1 += *(const f32x4*)(p + 4);
        }
        const f32x4 bi0 = *(const f32x4*)(b_in + (jb & 255));
        const f32x4 bi1 = *(const f32x4*)(b_in + (jb & 255) + 4);
        f32x4 c0, c1;
        #pragma unroll
        for (int e = 0; e < 4; ++e) {
            c0[e] = fmaxf(v0[e] + bi0[e], 0.0f);
            c1[e] = fmaxf(v1[e] + bi1[e], 0.0f);
        }
        *(f32x4*)&cw[jb]     = c0;
        *(f32x4*)&cw[jb + 4] = c1;
        __syncthreads();

        // x1[i] over 512-dim: half-waves handle j<256 / j>=256, then fold
        float p1 = 0.0f;
        #pragma unroll 8
        for (int jj = 0; jj < 256; ++jj) {
            const int j = lh * 256 + jj;
            p1 = fmaf((float)W1h[j * 32 + (l31 ^ (jj & 31))], cw[j], p1);
        }
        p1 += __shfl_xor(p1, 32);
        const float x1 = fmaxf(p1 + bh1, 0.0f);

        // x2[i'] = sum_i W_h2[i'][i] * x1[i], broadcast x1 via shfl
        float p2 = 0.0f;
        #pragma unroll
        for (int ii = 0; ii < 32; ++ii) {
            const float xv = __shfl(x1, ii);
            p2 = fmaf(W2T[ii * 33 + l31], xv, p2);
        }
        const float x2 = fmaxf(p2 + bh2, 0.0f);

        float ov = x2 * Wo[l31];
        ov += __shfl_xor(ov, 16);
        ov += __shfl_xor(ov, 8);
        ov += __shfl_xor(ov, 4);
        ov += __shfl_xor(ov, 2);
        ov += __shfl_xor(ov, 1);
        if (lane == 0) out[row] = ov + bo;
        __syncthreads();
    }
}

extern "C" void kernel_launch(void* const* d_in, const int* in_sizes, int n_in,
                              void* d_out, int out_size, void* d_ws, size_t ws_size,
                              hipStream_t stream) {
    const float* wf   = (const float*)d_in[0];
    const float* blf  = (const float*)d_in[1];
    const float* Win  = (const float*)d_in[2];
    const float* bin  = (const float*)d_in[3];
    const float* Wh1  = (const float*)d_in[4];
    const float* bh1  = (const float*)d_in[5];
    const float* Wh2  = (const float*)d_in[6];
    const float* bh2  = (const float*)d_in[7];
    const float* Wout = (const float*)d_in[8];
    const float* bout = (const float*)d_in[9];
    float* out = (float*)d_out;

    _Float16* Wh   = (_Float16*)d_ws;
    float*    part = (float*)((char*)d_ws + WH_BYTES);

    // ws-adaptive split count: 21 MB packed-W copy + ks * 4 MB partials
    int ks = 1, use_atomic = 0;
    if (ws_size >= WH_BYTES + ACCN * 4) {
        ks = (int)((ws_size - WH_BYTES) / (ACCN * 4));
        if (ks > 16) ks = 16;
    } else {
        use_atomic = 1;  // needs ws >= 25.2 MB
    }

    pack_w_k<<<NBK, 256, 0, stream>>>(Win, Wh);
    if (use_atomic) zero_ws_k<<<512, 512, 0, stream>>>(part);
    dim3 g(MTOT / MT, ks);
    gemm_in_k<<<g, 512, 0, stream>>>(wf, blf, Wh, part, ks, use_atomic);
    mlp_k<<<BATCH / 8, 256, 0, stream>>>(part, use_atomic ? 1 : ks,
                                         bin, Wh1, bh1, Wh2, bh2, Wout, bout, out);
}

// Round 5
// 789.673 us; speedup vs baseline: 1.0635x; 1.0635x over previous
//
#include <hip/hip_runtime.h>

#define FEAT 41024
#define HID  256
#define BATCH 2048
#define MTOT 4096
#define MT 64
#define BK 64
#define NBK (FEAT / BK)                    /* 641 */
#define ACCN ((size_t)MTOT * HID)          /* 1,048,576 floats = 4 MB */
#define WH_BYTES ((size_t)HID * FEAT * 2)  /* 21,004,288 bytes, packed f16 W_in */
#define SLAB_ELTS 16384                    /* HID*BK f16 per k-slab in pack */

typedef float    f32x4  __attribute__((ext_vector_type(4)));
typedef float    f32x16 __attribute__((ext_vector_type(16)));
typedef _Float16 f16x4  __attribute__((ext_vector_type(4)));
typedef _Float16 f16x8  __attribute__((ext_vector_type(8)));

// ---------------- zero kernel (atomic-fallback path only) ----------------
__global__ __launch_bounds__(512) void zero_ws_k(float* __restrict__ p) {
    int i = blockIdx.x * 512 + threadIdx.x;
    ((f32x4*)p)[i] = (f32x4)(0.0f);
}

// ---------------- W_in fp32 -> f16 fragment-linear pack (one-shot) ----------------
// One block per k-slab t. Output layout: frag = wn*8 + ks*2 + nf (0..31), lane l, elem e:
//   P[t*16384 + frag*512 + l*8 + e] = (f16) W[wn*64 + nf*32 + (l&31)][t*64 + (ks*2+(l>>5))*8 + e]
// Byte-identical to what R2's verified LDS staging+swizzle delivered to the MFMA
// B-operand, so gemm numerics are unchanged.
__global__ __launch_bounds__(256) void pack_w_k(
    const float* __restrict__ W, _Float16* __restrict__ P)
{
    __shared__ _Float16 Ls[256 * 64];  // 32 KB: W[0:256][t*64 : t*64+64] in f16
    const int t = blockIdx.x, tid = threadIdx.x;
    const int rr = tid >> 3, cc = tid & 7;
    #pragma unroll
    for (int u = 0; u < 8; ++u) {
        const int row = u * 32 + rr;
        const float* src = W + (size_t)row * FEAT + t * 64 + cc * 8;
        f32x4 v0 = *(const f32x4*)src;
        f32x4 v1 = *(const f32x4*)(src + 4);
        f16x8 h;
        #pragma unroll
        for (int e = 0; e < 4; ++e) { h[e] = (_Float16)v0[e]; h[e + 4] = (_Float16)v1[e]; }
        *(f16x8*)&Ls[row * 64 + cc * 8] = h;
    }
    __syncthreads();
    #pragma unroll
    for (int u = 0; u < 8; ++u) {
        const int flat = u * 256 + tid;          // 0..2047: one 16B output chunk
        const int frag = flat >> 6, l = flat & 63;
        const int wn = frag >> 3, ks = (frag >> 1) & 3, nf = frag & 1;
        const int row = wn * 64 + nf * 32 + (l & 31);
        const int kc  = ks * 2 + (l >> 5);
        *(f16x8*)&P[(size_t)t * SLAB_ELTS + (size_t)flat * 8] =
            *(const f16x8*)&Ls[row * 64 + kc * 8];
    }
}

// ---------------- input-layer GEMM: [4096,41024] x [41024,256]^T ----------------
// 512 threads = 8 waves (2m x 4n), block tile 64(M) x 256(N), wave tile 32x64.
// R4 post-mortem: the tight in-cluster B-refill variant miscomputed (toolchain-level
// ordering fragility, rule-#18 family) -- reverted to R3's harness-verified dataflow:
// B double-buffered in registers (bcur/bnxt), A-prefetch depth 2 (pa0/pa1).
// R3's defect (scratch spill: WRITE_SIZE 64->327 MB) is fixed by the one orthogonal
// knob: __launch_bounds__(512,2) gives 256 regs/lane so the ~145-reg working set
// fits with no spill. 1 block/CU; all HBM/L2 waits are a full iteration (~1.6K cyc)
// after issue with ~96 KB/CU in flight >= Little's-law need (~22 KB); the only
// barrier-adjacent wait is lgkmcnt on the 16 KB A ds-write.
__global__ __launch_bounds__(512, 2) void gemm_in_k(
    const float* __restrict__ wfeat, const float* __restrict__ bfeat,
    const _Float16* __restrict__ packW, float* __restrict__ part,
    int ksplit, int use_atomic)
{
    __shared__ __align__(16) _Float16 As[2][MT * BK];    // 2 x 8 KB

    const int tid   = threadIdx.x;
    const int mtile = blockIdx.x;
    const int split = blockIdx.y;
    const int it_beg = (split * NBK) / ksplit;
    const int it_end = ((split + 1) * NBK) / ksplit;
    const int L = it_end - it_beg;

    const int m0 = mtile * MT;  // block entirely white or entirely black rows
    const float* Aptr = (m0 < BATCH) ? (wfeat + (size_t)m0 * FEAT)
                                     : (bfeat + (size_t)(m0 - BATCH) * FEAT);

    // A staging: thread -> (row 0..63, 16B chunk 0..7); one f16x8 chunk per thread
    const int arow = tid >> 3;
    const int aqk  = tid & 7;
    const float* Asrc = Aptr + (size_t)arow * FEAT + aqk * 8;
    const int ac = aqk ^ (arow & 7);                     // XOR-swizzled chunk slot

    const int wid = tid >> 6, lane = tid & 63;
    const int l31 = lane & 31, lh = lane >> 5;
    const int wm  = wid >> 2;                            // 0..1
    const int wn  = wid & 3;                             // 0..3

    // B fragments: wave-contiguous 8 KB strip per slab, 8 x 1KB coalesced loads
    const _Float16* Bb = packW + (size_t)it_beg * SLAB_ELTS + wn * 4096 + lane * 8;

    f32x16 acc[2];
    acc[0] = (f32x16)(0.0f);
    acc[1] = (f32x16)(0.0f);

    f16x8 bcur[8], bnxt[8];
    f32x4 pa0[2], pa1[2];

    // ---- prologue: A(0)+B(0) now; A(1)+B(1) in flight; cvt A(0) -> As[0] ----
    {
        const int k0 = it_beg * BK;
        f32x4 a0 = *(const f32x4*)(Asrc + k0);
        f32x4 a1 = *(const f32x4*)(Asrc + k0 + 4);
        #pragma unroll
        for (int f = 0; f < 8; ++f) bcur[f] = *(const f16x8*)(Bb + f * 512);
        if (L > 1) {
            const float* s = Asrc + k0 + BK;
            pa0[0] = *(const f32x4*)s;
            pa0[1] = *(const f32x4*)(s + 4);
            #pragma unroll
            for (int f = 0; f < 8; ++f)
                bnxt[f] = *(const f16x8*)(Bb + SLAB_ELTS + f * 512);
        }
        f16x8 h;
        #pragma unroll
        for (int e = 0; e < 4; ++e) { h[e] = (_Float16)a0[e]; h[e + 4] = (_Float16)a1[e]; }
        *(f16x8*)&As[0][arow * BK + ac * 8] = h;
        asm volatile("s_waitcnt lgkmcnt(0)" ::: "memory");
        __builtin_amdgcn_sched_barrier(0);
        __builtin_amdgcn_s_barrier();
    }

    // entry invariants: As[bufc]=A(i); bC=B(i); other b-set=B(i+1) in flight;
    // paC=A(i+1) raw in flight; paN free.
    auto iter_body = [&](int i, int bufc, f16x8 (&bC)[8],
                         f32x4 (&paC)[2], f32x4 (&paN)[2]) {
        const bool hasW = (i + 1 < L);
        const bool has2 = (i + 2 < L);

        if (has2) {  // issue A(i+2) raw loads (HBM; waited next iteration)
            const float* s = Asrc + (size_t)(it_beg + i + 2) * BK;
            paN[0] = *(const f32x4*)s;
            paN[1] = *(const f32x4*)(s + 4);
        }
        if (hasW) {  // cvt A(i+1) -> other LDS buffer (safe: A(i-1) readers done)
            f16x8 h;
            #pragma unroll
            for (int e = 0; e < 4; ++e) {
                h[e]     = (_Float16)paC[0][e];
                h[e + 4] = (_Float16)paC[1][e];
            }
            *(f16x8*)&As[bufc ^ 1][arow * BK + ac * 8] = h;
        }

        // MFMA over slab i: A frags from LDS, B frags from registers
        #pragma unroll
        for (int ks = 0; ks < 4; ++ks) {
            const int r = wm * 32 + l31;
            const int c = (ks * 2 + lh) ^ (r & 7);
            const f16x8 afr = *(const f16x8*)&As[bufc][r * BK + c * 8];
            acc[0] = __builtin_amdgcn_mfma_f32_32x32x16_f16(afr, bC[ks * 2 + 0], acc[0], 0, 0, 0);
            acc[1] = __builtin_amdgcn_mfma_f32_32x32x16_f16(afr, bC[ks * 2 + 1], acc[1], 0, 0, 0);
        }

        if (has2) {  // refill just-consumed b-set with B(i+2) (waited in iter i+2)
            #pragma unroll
            for (int f = 0; f < 8; ++f)
                bC[f] = *(const f16x8*)(Bb + (size_t)(i + 2) * SLAB_ELTS + f * 512);
        }

        if (hasW) {
            asm volatile("s_waitcnt lgkmcnt(0)" ::: "memory");  // A ds ops done
            __builtin_amdgcn_sched_barrier(0);
            __builtin_amdgcn_s_barrier();                       // A(i+1) buffer ready
        }
    };

    int i = 0;
    while (true) {
        iter_body(i, 0, bcur, pa0, pa1);
        if (++i == L) break;
        iter_body(i, 1, bnxt, pa1, pa0);
        if (++i == L) break;
    }

    // epilogue: C/D layout col=lane&31, row=(reg&3)+8*(reg>>2)+4*(lane>>5)
    float* dst = part + (use_atomic ? (size_t)0 : (size_t)split * ACCN);
    #pragma unroll
    for (int nf = 0; nf < 2; ++nf) {
        const int gcol = wn * 64 + nf * 32 + l31;
        #pragma unroll
        for (int r = 0; r < 16; ++r) {
            const int rrow = (r & 3) + 8 * (r >> 2) + 4 * lh;
            const int grow = m0 + wm * 32 + rrow;
            const size_t idx = (size_t)grow * HID + gcol;
            if (use_atomic) atomicAdd(&dst[idx], acc[nf][r]);
            else            dst[idx] = acc[nf][r];
        }
    }
}

// ---------------- split-K reduce + bias/relu + tiny MLP ----------------
// 256 blocks x 256 threads; wave handles 2 batch rows. Lane owns MLP output i=lane&31;
// half-waves split the 512-wide concat dimension.
__global__ __launch_bounds__(256) void mlp_k(
    const float* __restrict__ part, int nparts,
    const float* __restrict__ b_in,
    const float* __restrict__ W_h1, const float* __restrict__ b_h1,
    const float* __restrict__ W_h2, const float* __restrict__ b_h2,
    const float* __restrict__ W_out, const float* __restrict__ b_out,
    float* __restrict__ out)
{
    __shared__ _Float16 W1h[512 * 32];  // transposed [j][i], XOR-swizzled, 32 KB
    __shared__ float    W2T[32 * 33];   // transposed [ii][i'], padded
    __shared__ float    Wo[32];
    __shared__ float    cbuf[4 * 512];  // per-wave combined vector

    const int tid = threadIdx.x;
    #pragma unroll
    for (int u = 0; u < 64; ++u) {
        const int f = tid + 256 * u;
        const int i = f >> 9, j = f & 511;
        W1h[j * 32 + (i ^ (j & 31))] = (_Float16)W_h1[i * 512 + j];
    }
    #pragma unroll
    for (int u = 0; u < 4; ++u) {
        const int f = tid + 256 * u;
        const int a = f >> 5, b = f & 31;
        W2T[b * 33 + a] = W_h2[a * 32 + b];
    }
    if (tid < 32) Wo[tid] = W_out[tid];
    __syncthreads();

    const int wid = tid >> 6, lane = tid & 63, l31 = lane & 31, lh = lane >> 5;
    const float bh1 = b_h1[l31], bh2 = b_h2[l31], bo = b_out[0];
    float* cw = &cbuf[wid * 512];

    for (int r = 0; r < 2; ++r) {
        const int row = blockIdx.x * 8 + wid * 2 + r;
        const int jb  = lane * 8;  // 0..504; lanes 0-31 white half, 32-63 black half
        const size_t srow = (size_t)(lh ? (row + BATCH) : row) * HID + (jb & 255);
        f32x4 v0 = (f32x4)(0.0f), v1 = (f32x4)(0.0f);
        for (int s = 0; s < nparts; ++s) {
            const float* p = part + (size_t)s * ACCN + srow;
            v0 += *(const f32x4*)p;
            v1 += *(const f32x4*)(p + 4);
        }
        const f32x4 bi0 = *(const f32x4*)(b_in + (jb & 255));
        const f32x4 bi1 = *(const f32x4*)(b_in + (jb & 255) + 4);
        f32x4 c0, c1;
        #pragma unroll
        for (int e = 0; e < 4; ++e) {
            c0[e] = fmaxf(v0[e] + bi0[e], 0.0f);
            c1[e] = fmaxf(v1[e] + bi1[e], 0.0f);
        }
        *(f32x4*)&cw[jb]     = c0;
        *(f32x4*)&cw[jb + 4] = c1;
        __syncthreads();

        // x1[i] over 512-dim: half-waves handle j<256 / j>=256, then fold
        float p1 = 0.0f;
        #pragma unroll 8
        for (int jj = 0; jj < 256; ++jj) {
            const int j = lh * 256 + jj;
            p1 = fmaf((float)W1h[j * 32 + (l31 ^ (jj & 31))], cw[j], p1);
        }
        p1 += __shfl_xor(p1, 32);
        const float x1 = fmaxf(p1 + bh1, 0.0f);

        // x2[i'] = sum_i W_h2[i'][i] * x1[i], broadcast x1 via shfl
        float p2 = 0.0f;
        #pragma unroll
        for (int ii = 0; ii < 32; ++ii) {
            const float xv = __shfl(x1, ii);
            p2 = fmaf(W2T[ii * 33 + l31], xv, p2);
        }
        const float x2 = fmaxf(p2 + bh2, 0.0f);

        float ov = x2 * Wo[l31];
        ov += __shfl_xor(ov, 16);
        ov += __shfl_xor(ov, 8);
        ov += __shfl_xor(ov, 4);
        ov += __shfl_xor(ov, 2);
        ov += __shfl_xor(ov, 1);
        if (lane == 0) out[row] = ov + bo;
        __syncthreads();
    }
}

extern "C" void kernel_launch(void* const* d_in, const int* in_sizes, int n_in,
                              void* d_out, int out_size, void* d_ws, size_t ws_size,
                              hipStream_t stream) {
    const float* wf   = (const float*)d_in[0];
    const float* blf  = (const float*)d_in[1];
    const float* Win  = (const float*)d_in[2];
    const float* bin  = (const float*)d_in[3];
    const float* Wh1  = (const float*)d_in[4];
    const float* bh1  = (const float*)d_in[5];
    const float* Wh2  = (const float*)d_in[6];
    const float* bh2  = (const float*)d_in[7];
    const float* Wout = (const float*)d_in[8];
    const float* bout = (const float*)d_in[9];
    float* out = (float*)d_out;

    _Float16* Wh   = (_Float16*)d_ws;
    float*    part = (float*)((char*)d_ws + WH_BYTES);

    // ws-adaptive split count: 21 MB packed-W copy + ks * 4 MB partials
    int ks = 1, use_atomic = 0;
    if (ws_size >= WH_BYTES + ACCN * 4) {
        ks = (int)((ws_size - WH_BYTES) / (ACCN * 4));
        if (ks > 16) ks = 16;
    } else {
        use_atomic = 1;  // needs ws >= 25.2 MB
    }

    pack_w_k<<<NBK, 256, 0, stream>>>(Win, Wh);
    if (use_atomic) zero_ws_k<<<512, 512, 0, stream>>>(part);
    dim3 g(MTOT / MT, ks);
    gemm_in_k<<<g, 512, 0, stream>>>(wf, blf, Wh, part, ks, use_atomic);
    mlp_k<<<BATCH / 8, 256, 0, stream>>>(part, use_atomic ? 1 : ks,
                                         bin, Wh1, bh1, Wh2, bh2, Wout, bout, out);
}